// Round 2
// baseline (355.650 us; speedup 1.0000x reference)
//
#include <hip/hip_runtime.h>

// ZeroWeave: x[B,C,H,W] -> out[B,C,190,190], out[:,:,::3,::3] = x, rest zero.
// Shapes fixed: B=32, C=64, H=W=64, num_zeros=2 (s=3).
//
// R1 analysis: flat-float4 version decoded (h,w) per ELEMENT (4 full magic
// div/mod chains + 4 predicated scattered loads per thread, ~120 VALU ops)
// -> VALU/latency-bound at ~2.1 TB/s effective vs 6.3 TB/s fill ceiling.
//
// R2: one float2 per thread. A row is 190 floats = exactly 95 float2, so a
// float2 NEVER crosses a row boundary: decode is one div-95 + one div-190 +
// one mod-3. Zero rows (2/3 of threads, mostly wave-uniform) store float2(0,0)
// immediately. Nonzero rows: a float2 {w0,w0+1} contains at most ONE multiple
// of 3 -> at most one scalar load. Grid covers output exactly, no tail.

constexpr int S  = 3;
constexpr int H  = 64;
constexpr int W  = 64;
constexpr int OH = H * S - (S - 1);          // 190
constexpr int OW = W * S - (S - 1);          // 190
constexpr int PLANE_IN = H * W;              // 4096
constexpr int ROW2 = OW / 2;                 // 95 float2 per row (exact)
constexpr long long N_OUT = 32LL * 64 * OH * OW;   // 73,932,800
constexpr int N2 = (int)(N_OUT / 2);         // 36,966,400 float2
constexpr int BLOCK = 256;
constexpr int GRID = N2 / BLOCK;             // 144,400 (exact)
static_assert(GRID * BLOCK == N2, "grid must cover output exactly");
static_assert(OW % 2 == 0, "row must be whole float2s");

__global__ __launch_bounds__(BLOCK) void ZeroWeave_89601607729830_kernel(
    const float* __restrict__ x, float* __restrict__ out) {
    int i = blockIdx.x * BLOCK + threadIdx.x;   // float2 index, < N2 always

    int row = i / ROW2;           // global row = bc*190 + h   (magic div 95)
    int j   = i - row * ROW2;     // float2 index within row
    int bc  = row / OH;           // (magic div 190)
    int h   = row - bc * OH;

    float2 v = make_float2(0.0f, 0.0f);
    if (h % S == 0) {
        int w0 = 2 * j;
        int m  = w0 % S;          // which of {w0, w0+1} is a multiple of 3
        const float* xr = x + bc * PLANE_IN + (h / S) * W;
        if (m == 0)      v.x = xr[w0 / S];
        else if (m == 2) v.y = xr[(w0 + 1) / S];
        // m == 1: neither element is a multiple of 3 -> stays zero
    }

    reinterpret_cast<float2*>(out)[i] = v;
}

extern "C" void kernel_launch(void* const* d_in, const int* in_sizes, int n_in,
                              void* d_out, int out_size, void* d_ws, size_t ws_size,
                              hipStream_t stream) {
    const float* x = (const float*)d_in[0];
    // d_in[1] is num_zeros (==2), baked into the constants above.
    float* out = (float*)d_out;

    ZeroWeave_89601607729830_kernel<<<GRID, BLOCK, 0, stream>>>(x, out);
}

// Round 3
// 328.406 us; speedup vs baseline: 1.0830x; 1.0830x over previous
//
#include <hip/hip_runtime.h>

// ZeroWeave: x[B,C,64,64] -> out[B,C,190,190], out[:,:,::3,::3]=x, rest 0.
// B=32, C=64, num_zeros=2 (s=3). out = 295.7 MB, x = 33.5 MB.
//
// R1/R2 post-mortem: one-chunk-per-thread kernels (72k-144k workgroups,
// wave lives for a single store that depends on a scattered HBM load) run at
// ~2 TB/s while the harness fill kernel hits 6.3 TB/s. VALU was ruled out
// (R1 ~120 ops/thread vs R2 ~20, identical time). Bottleneck: wave churn +
// load->store serialization, too few stores in flight per wave.
//
// R3: fill-shaped kernel. One block per (b,c) plane (2048 blocks = 8/CU =
// 32 waves/CU max occupancy). Stage the 16 KB x-plane into LDS (coalesced
// float4), then each thread streams ~36 float4 stores back-to-back; the
// gather feeding each store hits LDS (~120 cyc), not HBM (~900 cyc).
// Plane = 190*190 floats = 9025 float4 exactly; plane byte offset
// bc*144400 is 16B-aligned -> flat float4 stores stay aligned.
//
// Exact small-range magic division (verified bounds):
//   e/190  = (e*44151)>>23   exact for e < 102300  (we have e < 36100)
//   n/3    = (n*171)>>9      exact for n < 512     (we have n < 190)

constexpr int H = 64, W = 64;
constexpr int OH = 190, OW = 190;
constexpr int PLANE_IN = H * W;            // 4096 floats = 16 KB
constexpr int PLANE_OUT4 = OH * OW / 4;    // 9025 float4
constexpr int NPLANES = 32 * 64;           // 2048
constexpr int BLOCK = 256;
constexpr int FULL_ITERS = PLANE_OUT4 / BLOCK;       // 35
constexpr int TAIL = PLANE_OUT4 - FULL_ITERS * BLOCK; // 65

__global__ __launch_bounds__(BLOCK) void ZeroWeave_89601607729830_kernel(
    const float* __restrict__ x, float* __restrict__ out) {
    __shared__ float lds[PLANE_IN];

    const int bc  = blockIdx.x;
    const int tid = threadIdx.x;

    // Stage x plane -> LDS (1024 float4, 4 per thread, coalesced).
    {
        const float4* xp = reinterpret_cast<const float4*>(x + bc * PLANE_IN);
        float4* l4 = reinterpret_cast<float4*>(lds);
#pragma unroll
        for (int k = 0; k < PLANE_IN / 4 / BLOCK; ++k)
            l4[k * BLOCK + tid] = xp[k * BLOCK + tid];
    }
    __syncthreads();

    float4* op = reinterpret_cast<float4*>(out) + bc * PLANE_OUT4;

    auto emit = [&](int q) {
        const int e0 = q * 4;
        float4 v;
        float* vp = reinterpret_cast<float*>(&v);
#pragma unroll
        for (int j = 0; j < 4; ++j) {
            unsigned e = (unsigned)(e0 + j);
            unsigned h = (e * 44151u) >> 23;      // e / 190, exact
            unsigned w = e - h * 190u;
            unsigned h3 = (h * 171u) >> 9;        // h / 3, exact
            unsigned hm = h - h3 * 3u;
            unsigned w3 = (w * 171u) >> 9;        // w / 3, exact
            unsigned wm = w - w3 * 3u;
            float val = 0.0f;
            if ((hm | wm) == 0u) val = lds[(h3 << 6) + w3];
            vp[j] = val;
        }
        op[q] = v;
    };

#pragma unroll 4
    for (int k = 0; k < FULL_ITERS; ++k)
        emit(k * BLOCK + tid);
    if (tid < TAIL)
        emit(FULL_ITERS * BLOCK + tid);
}

extern "C" void kernel_launch(void* const* d_in, const int* in_sizes, int n_in,
                              void* d_out, int out_size, void* d_ws, size_t ws_size,
                              hipStream_t stream) {
    const float* x = (const float*)d_in[0];
    // d_in[1] is num_zeros (==2), baked into constants.
    float* out = (float*)d_out;

    ZeroWeave_89601607729830_kernel<<<NPLANES, BLOCK, 0, stream>>>(x, out);
}

// Round 4
// 327.859 us; speedup vs baseline: 1.0848x; 1.0017x over previous
//
#include <hip/hip_runtime.h>

// ZeroWeave: x[B,C,64,64] -> out[B,C,190,190], out[:,:,::3,::3]=x, rest 0.
// B=32, C=64, num_zeros=2 (s=3). out = 295.7 MB (must be fully written:
// harness poisons d_out), x = 33.5 MB. Memory floor ~52 us at 6.3 TB/s.
//
// R3 post-mortem: one block/plane + LDS-staged x got ~125 us (~2.6 TB/s).
// Aggregate VALU (~16 us) and memory (~52 us) don't explain it; the R3 inner
// loop had 4 exec-mask branch regions per float4 (144 exec toggles/thread)
// and ~80 VALU decode ops BETWEEN stores -> per-wave store issue is gated by
// decode/branch serialization, not bandwidth.
//
// R4: branchless table-driven compose. The output pattern is periodic:
// 6 rows = 1140 floats = exactly 285 float4, and 6-row groups are 16B-aligned
// (4560 B). Plane = 9025 float4 = 31 full groups + 190-float4 partial group
// (rows 186..189 == pattern rows 0..3, so it reuses table entries 0..189).
// Per-block: build 285-entry uchar4 table (float4-slot -> 4 x-offsets within
// the group's 128-float x-chunk; 255 = zero), stage x plane (16 KB) in LDS.
// Inner loop per float4: 1 magic-div + 1 table ds_read + 4 unconditional
// masked LDS reads + 4 cndmask + 1 store. No branches, no exec toggles.
//
// Exact magic divs (range-verified):
//   e/190 = (e*44151)>>23  exact for e < 102300 (used with e < 1140)
//   n/3   = (n*171)>>9     exact for n < 512    (used with n < 190)
//   q/285 = (q*58868)>>24  exact for q <= 9024  (58868*285-2^24=164;
//                           164*9024 < 2^24; 9024*58868 < 2^32)

constexpr int PLANE_IN   = 64 * 64;          // 4096 floats = 16 KB
constexpr int PLANE_OUT4 = 190 * 190 / 4;    // 9025 float4
constexpr int GROUP4     = 285;              // float4 per 6-row group
constexpr int NPLANES    = 32 * 64;          // 2048
constexpr int BLOCK      = 256;
constexpr int FULL_ITERS = PLANE_OUT4 / BLOCK;            // 35
constexpr int TAIL       = PLANE_OUT4 - FULL_ITERS * BLOCK; // 65

__global__ __launch_bounds__(BLOCK, 8) void ZeroWeave_89601607729830_kernel(
    const float* __restrict__ x, float* __restrict__ out) {
    __shared__ float    xs[PLANE_IN];
    __shared__ unsigned tab[GROUP4];

    const int bc = blockIdx.x;
    const int t  = threadIdx.x;

    // Stage x plane -> LDS (1024 float4, coalesced).
    {
        const float4* xp = reinterpret_cast<const float4*>(x + bc * PLANE_IN);
        float4* xl = reinterpret_cast<float4*>(xs);
#pragma unroll
        for (int k = 0; k < PLANE_IN / 4 / BLOCK; ++k)
            xl[k * BLOCK + t] = xp[k * BLOCK + t];
    }

    // Build the 285-entry pattern table (2 rounds; once per block, ~free).
    for (int p = t; p < GROUP4; p += BLOCK) {
        unsigned packed = 0;
#pragma unroll
        for (int j = 0; j < 4; ++j) {
            unsigned e  = 4u * p + j;              // element within group, <1140
            unsigned h  = (e * 44151u) >> 23;      // e / 190 (pattern row 0..5)
            unsigned w  = e - h * 190u;
            unsigned h3 = (h * 171u) >> 9;         // h / 3 (0 or 1)
            unsigned hm = h - h3 * 3u;
            unsigned w3 = (w * 171u) >> 9;         // w / 3
            unsigned wm = w - w3 * 3u;
            unsigned src = ((hm | wm) == 0u) ? (h3 * 64u + w3) : 255u; // <128 or 255
            packed |= src << (8 * j);
        }
        tab[p] = packed;
    }
    __syncthreads();

    float4* op = reinterpret_cast<float4*>(out) + bc * PLANE_OUT4;

    auto emit = [&](int q) {
        unsigned g     = ((unsigned)q * 58868u) >> 24;  // q / 285, exact q<=9024
        unsigned p     = (unsigned)q - g * 285u;
        unsigned xbase = g << 7;                        // group's x chunk (128 floats)
        unsigned packed = tab[p];
        float4 v;
        float* vp = reinterpret_cast<float*>(&v);
#pragma unroll
        for (int j = 0; j < 4; ++j) {
            unsigned b = (packed >> (8 * j)) & 255u;
            float val  = xs[(xbase + b) & (PLANE_IN - 1)]; // always in-bounds
            vp[j] = (b != 255u) ? val : 0.0f;              // cndmask, no branch
        }
        op[q] = v;
    };

#pragma unroll 4
    for (int k = 0; k < FULL_ITERS; ++k)
        emit(k * BLOCK + t);
    if (t < TAIL)
        emit(FULL_ITERS * BLOCK + t);
}

extern "C" void kernel_launch(void* const* d_in, const int* in_sizes, int n_in,
                              void* d_out, int out_size, void* d_ws, size_t ws_size,
                              hipStream_t stream) {
    const float* x = (const float*)d_in[0];
    // d_in[1] is num_zeros (==2), baked into constants.
    float* out = (float*)d_out;

    ZeroWeave_89601607729830_kernel<<<NPLANES, BLOCK, 0, stream>>>(x, out);
}